// Round 3
// baseline (530.682 us; speedup 1.0000x reference)
//
#include <hip/hip_runtime.h>
#include <hip/hip_bf16.h>

typedef unsigned short u16;
typedef unsigned int   u32;
typedef __bf16 bf16x8 __attribute__((ext_vector_type(8)));
typedef float  f32x4  __attribute__((ext_vector_type(4)));
typedef u32    u32x2  __attribute__((ext_vector_type(2)));

#define KPAD 1088
#define PI_F 3.14159265358979323846f

__device__ __forceinline__ u16 f2bf(float f){
    u32 u = __float_as_uint(f);
    return (u16)((u + 0x7FFFu + ((u >> 16) & 1u)) >> 16);
}
__device__ __forceinline__ float bf2f(u16 v){ return __uint_as_float(((u32)v) << 16); }
__device__ __forceinline__ int zmap(int e){ return e + (e >> 4); }

// natural-order spectral index k -> physical LDS slot after the in-place 3-step FFT
// k = kI + 64*kO, kI = jv + 4*ju  ->  slot = kO + 16*ju + 256*jv (then zmap pad)
__device__ __forceinline__ int sig(int k){
    k &= 1023;
    int a = (k >> 6) + (((k >> 2) & 15) << 4) + ((k & 3) << 8);
    return zmap(a);
}

__device__ __forceinline__ float2 cmul(float2 a, float2 b){
    return make_float2(a.x*b.x - a.y*b.y, a.x*b.y + a.y*b.x);
}
// 4-point DFT, kernel e^{-2pi i v j/4}; in/out in place (slot v -> slot j)
__device__ __forceinline__ void fft4v(float2& x0, float2& x1, float2& x2, float2& x3){
    float2 t0 = make_float2(x0.x+x2.x, x0.y+x2.y);
    float2 t1 = make_float2(x0.x-x2.x, x0.y-x2.y);
    float2 t2 = make_float2(x1.x+x3.x, x1.y+x3.y);
    float2 t3 = make_float2(x1.x-x3.x, x1.y-x3.y);
    x0 = make_float2(t0.x+t2.x, t0.y+t2.y);
    x2 = make_float2(t0.x-t2.x, t0.y-t2.y);
    x1 = make_float2(t1.x+t3.y, t1.y-t3.x);   // t1 - i*t3
    x3 = make_float2(t1.x-t3.y, t1.y+t3.x);   // t1 + i*t3
}
// 16-point DFT (radix-4^2), input a[u], output X[j] at slot tau(j)=((j&3)<<2)|(j>>2)
__device__ __forceinline__ void fft16(float2 a[16]){
    #pragma unroll
    for (int u1 = 0; u1 < 4; ++u1) fft4v(a[u1], a[u1+4], a[u1+8], a[u1+12]);
    const float Cq = 0.70710678118654752f;
    const float c1 = 0.92387953251128674f, s1 = 0.38268343236508977f;
    a[5]  = cmul(a[5],  make_float2(c1, -s1));    // W16^1
    a[6]  = cmul(a[6],  make_float2(Cq, -Cq));    // W16^2
    a[7]  = cmul(a[7],  make_float2(s1, -c1));    // W16^3
    a[9]  = cmul(a[9],  make_float2(Cq, -Cq));    // W16^2
    a[10] = cmul(a[10], make_float2(0.0f, -1.0f));// W16^4
    a[11] = cmul(a[11], make_float2(-Cq, -Cq));   // W16^6
    a[13] = cmul(a[13], make_float2(s1, -c1));    // W16^3
    a[14] = cmul(a[14], make_float2(-Cq, -Cq));   // W16^6
    a[15] = cmul(a[15], make_float2(-c1, s1));    // W16^9
    #pragma unroll
    for (int ja = 0; ja < 4; ++ja) fft4v(a[4*ja], a[4*ja+1], a[4*ja+2], a[4*ja+3]);
}

// ---- in-place 3-step FFT over Zs[4][1088] (zmap-padded), 256 threads ----
// n = nA + 16u + 256v ; thread t: step A unit (nA=t&15, u=(t>>4)&15) all 4 seqs
__device__ __forceinline__ void fft_stepA_lds(float2* Zs, int tid){
    int u = (tid >> 4) & 15;
    float s_, c_;
    __sincosf(-2.0f*PI_F*(float)u*(1.0f/64.0f), &s_, &c_);
    float2 tw1 = make_float2(c_, s_);
    float2 tw2 = cmul(tw1, tw1);
    float2 tw3 = cmul(tw2, tw1);
    #pragma unroll
    for (int s = 0; s < 4; ++s){
        float2* Z = Zs + s*1088;
        float2 x0 = Z[zmap(tid)], x1 = Z[zmap(tid+256)], x2 = Z[zmap(tid+512)], x3 = Z[zmap(tid+768)];
        fft4v(x0, x1, x2, x3);
        Z[zmap(tid)]     = x0;
        Z[zmap(tid+256)] = cmul(x1, tw1);
        Z[zmap(tid+512)] = cmul(x2, tw2);
        Z[zmap(tid+768)] = cmul(x3, tw3);
    }
}
__device__ __forceinline__ void fft_stepB(float2* Zs, int tid){
    int seq = tid >> 6, id = tid & 63;
    int nA = id & 15, jv = id >> 4;
    float2* Z = Zs + seq*1088;
    float2 a[16];
    #pragma unroll
    for (int u = 0; u < 16; ++u) a[u] = Z[zmap(nA + 16*u + 256*jv)];
    fft16(a);
    float s_, c_;
    __sincosf(-2.0f*PI_F*(float)(nA*jv)*(1.0f/1024.0f), &s_, &c_);
    float2 tw = make_float2(c_, s_);
    __sincosf(-2.0f*PI_F*(float)nA*(1.0f/256.0f), &s_, &c_);
    float2 st = make_float2(c_, s_);
    #pragma unroll
    for (int ju = 0; ju < 16; ++ju){
        float2 v = cmul(a[((ju&3)<<2)|(ju>>2)], tw);
        Z[zmap(nA + 16*ju + 256*jv)] = v;
        tw = cmul(tw, st);
    }
}
__device__ __forceinline__ void fft_stepC(float2* Zs, int tid){
    int seq = tid >> 6, kI = tid & 63;
    int ju = kI >> 2, jv = kI & 3;
    float2* Z = Zs + seq*1088;
    float2 a[16];
    #pragma unroll
    for (int nA = 0; nA < 16; ++nA) a[nA] = Z[zmap(nA + 16*ju + 256*jv)];
    fft16(a);
    #pragma unroll
    for (int kO = 0; kO < 16; ++kO)
        Z[zmap(kO + 16*ju + 256*jv)] = a[((kO&3)<<2)|(kO>>2)];
}

// ---------------- weight prep: fp32 -> bf16, transposed ----------------
__global__ __launch_bounds__(256) void prep_w(const float* __restrict__ w1,
                                              const float* __restrict__ w2,
                                              u16* __restrict__ WSW){
    int gid = blockIdx.x * 256 + threadIdx.x;
    int qd = gid >> 12;
    int t  = qd & 1;
    int n  = (qd >> 1) & 7;
    int l  = qd >> 4;
    int rr = gid & 4095;
    int o  = rr >> 6;
    int k  = rr & 63;
    const float* w = l ? w2 : w1;
    WSW[gid] = f2bf(w[((size_t)(t*8 + n)*64 + k)*64 + o]);
}

// Spectrum layout: S[SIDX * KPAD + k], SIDX = (((b*8+c)*8+n)*2+pl)*64 + p_local

__device__ __forceinline__ u16 unpack_one(const float2* Zc, int k, int pl, float sf){
    float2 Zk = Zc[sig(k)], Zm = Zc[sig(1024 - k)];
    float sn_, cs_; __sincosf(PI_F*(float)k*(1.0f/1024.0f), &sn_, &cs_);
    float Er=0.5f*(Zk.x+Zm.x), Ei=0.5f*(Zk.y-Zm.y);
    float Dr=0.5f*(Zk.x-Zm.x), Di=0.5f*(Zk.y+Zm.y);
    float Xr = Er + cs_*Di - sn_*Dr;
    float Xi = Ei - sn_*Di - cs_*Dr;
    return f2bf((pl ? Xi : Xr) * sf);
}

// ---------------- forward rfft(2048) via packed complex FFT(1024) ----------------
__global__ __launch_bounds__(256) void fwd_fft(const float* __restrict__ X,
                                               u16* __restrict__ S){
    __shared__ float2 Zs[4*1088];
    int tid = threadIdx.x;
    int blk = blockIdx.x;
    int b = blk >> 10;
    int q = blk & 1023;
    int m8 = q & 7, tq = q >> 3;
    int Q = (tq >> 2)*8 + m8, s4 = tq & 3;
    int col0 = Q*16 + s4*4;
    int p  = col0 >> 3;
    int c0 = col0 & 7;
    int n  = p >> 6, pl_ = p & 63;

    // fused load + pack + step A (thread t's step-A inputs are exactly z[t+256v])
    float2 zz[4][4];   // [v][seq]
    #pragma unroll
    for (int v = 0; v < 4; ++v){
        int pi = tid + 256*v;
        size_t base = ((size_t)(b*2048 + 2*pi)*512 + p)*8 + c0;
        f32x4 ve = *(const f32x4*)(X + base);
        f32x4 vo = *(const f32x4*)(X + base + 4096);
        #pragma unroll
        for (int s = 0; s < 4; ++s) zz[v][s] = make_float2(ve[s], vo[s]);
    }
    {
        int u = (tid >> 4) & 15;
        float s_, c_;
        __sincosf(-2.0f*PI_F*(float)u*(1.0f/64.0f), &s_, &c_);
        float2 tw1 = make_float2(c_, s_);
        float2 tw2 = cmul(tw1, tw1);
        float2 tw3 = cmul(tw2, tw1);
        #pragma unroll
        for (int s = 0; s < 4; ++s){
            float2 x0 = zz[0][s], x1 = zz[1][s], x2 = zz[2][s], x3 = zz[3][s];
            fft4v(x0, x1, x2, x3);
            float2* Z = Zs + s*1088;
            Z[zmap(tid)]     = x0;
            Z[zmap(tid+256)] = cmul(x1, tw1);
            Z[zmap(tid+512)] = cmul(x2, tw2);
            Z[zmap(tid+768)] = cmul(x3, tw3);
        }
    }
    __syncthreads();
    fft_stepB(Zs, tid);
    __syncthreads();
    fft_stepC(Zs, tid);
    __syncthreads();
    // unpack + k-contiguous coalesced store
    const float sf = 0.02209708691207961f;     // 1/sqrt(2048)
    int run = tid >> 5, tr = tid & 31;
    int ci = run >> 1, pl = run & 1;
    const float2* Zc = Zs + ci*1088;
    u16* rp = S + (size_t)((((b*8 + (c0+ci))*8 + n)*2 + pl)*64 + pl_)*KPAD;
    for (int kk = tr*2; kk <= 1024; kk += 64){
        u16 w0 = unpack_one(Zc, kk, pl, sf);
        if (kk < 1024){
            u16 w1 = unpack_one(Zc, kk+1, pl, sf);
            *(u32*)(rp + kk) = (u32)w0 | ((u32)w1 << 16);
        } else {
            rp[kk] = w0;
        }
    }
}

// ---------------- MLP ----------------
__device__ __forceinline__ bf16x8 fetchB(const u16* mat, int o64, int k64, bool neg){
    const u32x2* pb = (const u32x2*)(mat + o64*68 + k64);
    u32x2 lo = pb[0], hi = pb[1];
    union { u32 u[4]; bf16x8 v; } bt;
    bt.u[0]=lo.x; bt.u[1]=lo.y; bt.u[2]=hi.x; bt.u[3]=hi.y;
    if (neg){ bt.u[0]^=0x80008000u; bt.u[1]^=0x80008000u; bt.u[2]^=0x80008000u; bt.u[3]^=0x80008000u; }
    return bt.v;
}
__device__ __forceinline__ bf16x8 loadU16x8(const u16* pp){
    union { u32 u[4]; bf16x8 v; } t;
    const u32* qq = (const u32*)pp;
    t.u[0]=qq[0]; t.u[1]=qq[1]; t.u[2]=qq[2]; t.u[3]=qq[3];
    return t.v;
}

__global__ __launch_bounds__(256) void mlp_kernel(const u16* __restrict__ WSW,
                                                  const float* __restrict__ b1,
                                                  const float* __restrict__ b2,
                                                  u16* __restrict__ S){
    __shared__ __align__(16) u16 AT[4][64*68];
    __shared__ __align__(16) u16 AS[8448];
    int tid = threadIdx.x;
    int blk = blockIdx.x;                // 1088 = 8n x 17t x 8bcg
    int n = blk & 7;
    int rest = blk >> 3;                 // 0..135
    int t17 = rest % 17;
    int bcg = rest / 17;                 // 0..7
    int k0 = t17 << 6;
    int lane = tid & 63, wv = tid >> 6;
    int lane15 = lane & 15, quad = lane >> 4;

    for (int mi = 0; mi < 4; ++mi){
        const u32* src = (const u32*)(WSW + (size_t)(((mi>>1)*8 + n)*2 + (mi&1))*4096);
        u32* dstm = (u32*)AT[mi];
        for (int d = tid; d < 2048; d += 256){
            int o = d >> 5, kk2 = d & 31;
            dstm[o*34 + kk2] = src[d];
        }
    }
    float bb1[8], bb2v[8];
    #pragma unroll
    for (int nb = 0; nb < 8; ++nb){
        int col = nb*16 + lane15;
        int tt = col >> 6, cc = col & 63;
        bb1[nb]  = b1[tt*512 + n*64 + cc];
        bb2v[nb] = b2[tt*512 + n*64 + cc];
    }
    __syncthreads();

    for (int it = 0; it < 4; ++it){
        int bc = bcg*4 + it;
        int b = bc >> 3, c = bc & 7;
        size_t SB = (size_t)(((b*8 + c)*8 + n)*2)*64;
        // stage A-tile: coalesced k-runs -> LDS transpose AS[k][f]
        {
            int rsub = tid & 31;
            for (int rr = tid >> 5; rr < 128; rr += 8){
                const u16* rp = S + (SB + rr)*KPAD + k0;
                u32 w = *(const u32*)(rp + 2*rsub);
                AS[(2*rsub)*132 + rr]   = (u16)(w & 0xFFFFu);
                AS[(2*rsub+1)*132 + rr] = (u16)(w >> 16);
            }
        }
        __syncthreads();
        // ---- layer 1 ----
        const u16* arow = AS + (wv*16 + lane15)*132;
        bf16x8 afr[4];
        #pragma unroll
        for (int kb = 0; kb < 4; ++kb)
            afr[kb] = loadU16x8(arow + kb*32 + quad*8);
        f32x4 acc[8];
        #pragma unroll
        for (int nb = 0; nb < 8; ++nb){ acc[nb][0]=bb1[nb]; acc[nb][1]=bb1[nb]; acc[nb][2]=bb1[nb]; acc[nb][3]=bb1[nb]; }
        #pragma unroll
        for (int nb = 0; nb < 8; ++nb){
            int o64 = (nb&3)*16 + lane15;
            #pragma unroll
            for (int kb = 0; kb < 4; ++kb){
                int k64 = (kb&1)*32 + quad*8;
                const u16* mat; bool neg = false;
                if (kb < 2) mat = (nb<4) ? AT[0] : AT[1];
                else { if (nb<4){ mat = AT[1]; neg = true; } else mat = AT[0]; }
                acc[nb] = __builtin_amdgcn_mfma_f32_16x16x32_bf16(afr[kb], fetchB(mat,o64,k64,neg), acc[nb], 0,0,0);
            }
        }
        // gelu -> H into this wave's own rows (in-wave read-before-write ordering)
        #pragma unroll
        for (int nb = 0; nb < 8; ++nb){
            #pragma unroll
            for (int r4 = 0; r4 < 4; ++r4){
                float xv = acc[nb][r4];
                float u_ = xv * 0.70710678118f;
                float u2 = u_*u_;
                float pg = 1.0f + u2*(-0.333333333f + u2*(0.1f + u2*(-0.0238095238f)));
                float h  = 0.5f * xv * (1.0f + 1.12837916709551f * u_ * pg);
                AS[(wv*16 + quad*4 + r4)*132 + nb*16 + lane15] = f2bf(h);
            }
        }
        // ---- layer 2 ----
        bf16x8 a2[4];
        #pragma unroll
        for (int kb = 0; kb < 4; ++kb)
            a2[kb] = loadU16x8(arow + kb*32 + quad*8);
        f32x4 acc2[8];
        #pragma unroll
        for (int nb = 0; nb < 8; ++nb){ acc2[nb][0]=bb2v[nb]; acc2[nb][1]=bb2v[nb]; acc2[nb][2]=bb2v[nb]; acc2[nb][3]=bb2v[nb]; }
        #pragma unroll
        for (int nb = 0; nb < 8; ++nb){
            int o64 = (nb&3)*16 + lane15;
            #pragma unroll
            for (int kb = 0; kb < 4; ++kb){
                int k64 = (kb&1)*32 + quad*8;
                const u16* mat; bool neg = false;
                if (kb < 2) mat = (nb<4) ? AT[2] : AT[3];
                else { if (nb<4){ mat = AT[3]; neg = true; } else mat = AT[2]; }
                acc2[nb] = __builtin_amdgcn_mfma_f32_16x16x32_bf16(a2[kb], fetchB(mat,o64,k64,neg), acc2[nb], 0,0,0);
            }
        }
        __syncthreads();   // all waves done with AS rows; reuse as OS
        #pragma unroll
        for (int nb = 0; nb < 8; ++nb){
            #pragma unroll
            for (int r4 = 0; r4 < 4; ++r4)
                AS[(nb*16 + lane15)*66 + (wv*16 + quad*4 + r4)] = f2bf(acc2[nb][r4]);
        }
        __syncthreads();
        // coalesced write-back (in-place; guard k<=1024)
        {
            int rsub = tid & 31;
            int k = k0 + 2*rsub;
            for (int rr = tid >> 5; rr < 128; rr += 8){
                u32 val = *(const u32*)(AS + rr*66 + 2*rsub);
                u16* rp = S + (SB + rr)*KPAD + k0;
                if (k + 1 <= 1024)  *(u32*)(rp + 2*rsub) = val;
                else if (k == 1024) rp[2*rsub] = (u16)(val & 0xFFFFu);
            }
        }
        __syncthreads();   // protect AS before next iteration's staging
    }
}

// ---------------- inverse: irfft(2048, ortho) + residual ----------------
__global__ __launch_bounds__(256) void inv_fft(const u16* __restrict__ S,
                                               const float* __restrict__ X,
                                               float* __restrict__ OUT){
    __shared__ float2 Zs[4*1088];
    __shared__ float2 ysp[4];
    int tid = threadIdx.x;
    int blk = blockIdx.x;
    int b = blk >> 10;
    int q = blk & 1023;
    int m8 = q & 7, tq = q >> 3;
    int Q = (tq >> 2)*8 + m8, s4 = tq & 3;
    int col0 = Q*16 + s4*4;
    int p  = col0 >> 3;
    int c0 = col0 & 7;
    int n  = p >> 6, pl_ = p & 63;

    // read spectrum: group g = channel c0+g, coalesced k-runs -> natural layout
    {
        int g = tid >> 6, l64 = tid & 63;
        const u16* rpR = S + (size_t)((((b*8 + (c0+g))*8 + n)*2 + 0)*64 + pl_)*KPAD;
        const u16* rpI = rpR + (size_t)64*KPAD;
        for (int kk = 2*l64; kk <= 1024; kk += 128){
            u32 wr = *(const u32*)(rpR + kk);
            u32 wi = *(const u32*)(rpI + kk);
            float yr0 = bf2f((u16)(wr & 0xFFFFu));
            float yi0 = bf2f((u16)(wi & 0xFFFFu));
            if (kk == 0)         Zs[g*1088 + zmap(0)] = make_float2(yr0, 0.0f);
            else if (kk == 1024) ysp[g] = make_float2(yr0, 0.0f);
            else                 Zs[g*1088 + zmap(kk)] = make_float2(yr0, yi0);
            if (kk < 1024){
                float yr1 = bf2f((u16)(wr >> 16));
                float yi1 = bf2f((u16)(wi >> 16));
                Zs[g*1088 + zmap(kk+1)] = make_float2(yr1, yi1);
            }
        }
    }
    __syncthreads();
    // hermitian pre-process (in place, pairwise): Z[k] = E + i*(e^{+i pi k/1024} * D)
    for (int k = tid; k <= 512; k += 256){
        float s2_, c2_; __sincosf(PI_F*(float)k*(1.0f/1024.0f), &s2_, &c2_);
        #pragma unroll
        for (int s = 0; s < 4; ++s){
            float2 Yk = Zs[s*1088 + zmap(k)];
            float2 Ym = (k == 0) ? ysp[s] : Zs[s*1088 + zmap(1024 - k)];
            float Ex = 0.5f*(Yk.x + Ym.x);
            float Ey = 0.5f*(Yk.y - Ym.y);
            float Dx = 0.5f*(Yk.x - Ym.x);
            float Dy = 0.5f*(Yk.y + Ym.y);
            float Ox = c2_*Dx - s2_*Dy;
            float Oy = c2_*Dy + s2_*Dx;
            Zs[s*1088 + zmap(k)] = make_float2(Ex - Oy, Ey + Ox);
            if (k > 0 && k < 512)
                Zs[s*1088 + zmap(1024 - k)] = make_float2(Ex + Oy, Ox - Ey);
        }
    }
    __syncthreads();
    fft_stepA_lds(Zs, tid);
    __syncthreads();
    fft_stepB(Zs, tid);
    __syncthreads();
    fft_stepC(Zs, tid);
    __syncthreads();
    // unpack interleaved (index reversal) + residual + float4 store
    const float sc = 0.04419417382415922f;   // sqrt(2048)/1024
    for (int pi = tid; pi < 1024; pi += 256){
        int zb = sig(1024 - pi);
        size_t base = ((size_t)(b*2048 + 2*pi)*512 + p)*8 + c0;
        f32x4 xe = *(const f32x4*)(X + base);
        f32x4 xo = *(const f32x4*)(X + base + 4096);
        f32x4 oe, oo;
        #pragma unroll
        for (int s = 0; s < 4; ++s){
            float2 r = Zs[s*1088 + zb];
            oe[s] = r.x*sc + xe[s];
            oo[s] = r.y*sc + xo[s];
        }
        *(f32x4*)(OUT + base)        = oe;
        *(f32x4*)(OUT + base + 4096) = oo;
    }
}

extern "C" void kernel_launch(void* const* d_in, const int* in_sizes, int n_in,
                              void* d_out, int out_size, void* d_ws, size_t ws_size,
                              hipStream_t stream){
    (void)in_sizes; (void)n_in; (void)out_size; (void)ws_size;
    const float* x  = (const float*)d_in[0];
    const float* w1 = (const float*)d_in[1];
    const float* b1 = (const float*)d_in[2];
    const float* w2 = (const float*)d_in[3];
    const float* b2 = (const float*)d_in[4];
    float* out = (float*)d_out;
    u16* WSW = (u16*)d_ws;
    u16* S1  = (u16*)((char*)d_ws + (1 << 20));

    prep_w<<<dim3(512),  dim3(256), 0, stream>>>(w1, w2, WSW);
    fwd_fft<<<dim3(4096), dim3(256), 0, stream>>>(x, S1);
    mlp_kernel<<<dim3(1088), dim3(256), 0, stream>>>(WSW, b1, b2, S1);
    inv_fft<<<dim3(4096), dim3(256), 0, stream>>>(S1, x, out);
}

// Round 4
// 493.632 us; speedup vs baseline: 1.0751x; 1.0751x over previous
//
#include <hip/hip_runtime.h>
#include <hip/hip_bf16.h>

typedef unsigned short u16;
typedef unsigned int   u32;
typedef __bf16 bf16x8 __attribute__((ext_vector_type(8)));
typedef float  f32x4  __attribute__((ext_vector_type(4)));
typedef u32    u32x2  __attribute__((ext_vector_type(2)));

#define KPAD 1088
#define SEQ  1104          // padded float2 slots per sequence (zmap2 max = 1098)
#define PI_F 3.14159265358979323846f
#define WAVE_FENCE() asm volatile("s_waitcnt lgkmcnt(0)" ::: "memory")

__device__ __forceinline__ u16 f2bf(float f){
    u32 u = __float_as_uint(f);
    return (u16)((u + 0x7FFFu + ((u >> 16) & 1u)) >> 16);
}
__device__ __forceinline__ float bf2f(u16 v){ return __uint_as_float(((u32)v) << 16); }
// pad: slot = e + (e>>4) + 4*(e>>8). injective on [0,1024); jv (bit8-9) shifts banks by 8.
__device__ __forceinline__ int zmap2(int e){ return e + (e >> 4) + 4*(e >> 8); }

// natural spectral index k -> physical LDS slot after the in-place 3-step FFT
// k = kI + 64*kO, kI = jv + 4*ju  ->  logical kO + 16*ju + 256*jv, then pad
__device__ __forceinline__ int sig(int k){
    k &= 1023;
    int a = (k >> 6) + (((k >> 2) & 15) << 4) + ((k & 3) << 8);
    return zmap2(a);
}

__device__ __forceinline__ float2 cmul(float2 a, float2 b){
    return make_float2(a.x*b.x - a.y*b.y, a.x*b.y + a.y*b.x);
}
__device__ __forceinline__ void fft4v(float2& x0, float2& x1, float2& x2, float2& x3){
    float2 t0 = make_float2(x0.x+x2.x, x0.y+x2.y);
    float2 t1 = make_float2(x0.x-x2.x, x0.y-x2.y);
    float2 t2 = make_float2(x1.x+x3.x, x1.y+x3.y);
    float2 t3 = make_float2(x1.x-x3.x, x1.y-x3.y);
    x0 = make_float2(t0.x+t2.x, t0.y+t2.y);
    x2 = make_float2(t0.x-t2.x, t0.y-t2.y);
    x1 = make_float2(t1.x+t3.y, t1.y-t3.x);
    x3 = make_float2(t1.x-t3.y, t1.y+t3.x);
}
// 16-point DFT, output X[j] at slot tau(j)=((j&3)<<2)|(j>>2)
__device__ __forceinline__ void fft16(float2 a[16]){
    #pragma unroll
    for (int u1 = 0; u1 < 4; ++u1) fft4v(a[u1], a[u1+4], a[u1+8], a[u1+12]);
    const float Cq = 0.70710678118654752f;
    const float c1 = 0.92387953251128674f, s1 = 0.38268343236508977f;
    a[5]  = cmul(a[5],  make_float2(c1, -s1));
    a[6]  = cmul(a[6],  make_float2(Cq, -Cq));
    a[7]  = cmul(a[7],  make_float2(s1, -c1));
    a[9]  = cmul(a[9],  make_float2(Cq, -Cq));
    a[10] = cmul(a[10], make_float2(0.0f, -1.0f));
    a[11] = cmul(a[11], make_float2(-Cq, -Cq));
    a[13] = cmul(a[13], make_float2(s1, -c1));
    a[14] = cmul(a[14], make_float2(-Cq, -Cq));
    a[15] = cmul(a[15], make_float2(-c1, s1));
    #pragma unroll
    for (int ja = 0; ja < 4; ++ja) fft4v(a[4*ja], a[4*ja+1], a[4*ja+2], a[4*ja+3]);
}

// ---- wave-local FFT phases: wave w operates only on Z = Zs + w*SEQ ----
__device__ __forceinline__ void fft_stepA_wave(float2* Z, int lane){
    #pragma unroll
    for (int i = 0; i < 4; ++i){
        int q = lane + 64*i;
        int u = (q >> 4) & 15;
        float s_, c_;
        __sincosf(-2.0f*PI_F*(float)u*(1.0f/64.0f), &s_, &c_);
        float2 tw1 = make_float2(c_, s_);
        float2 tw2 = cmul(tw1, tw1);
        float2 tw3 = cmul(tw2, tw1);
        float2 x0 = Z[zmap2(q)], x1 = Z[zmap2(q+256)], x2 = Z[zmap2(q+512)], x3 = Z[zmap2(q+768)];
        fft4v(x0, x1, x2, x3);
        Z[zmap2(q)]     = x0;
        Z[zmap2(q+256)] = cmul(x1, tw1);
        Z[zmap2(q+512)] = cmul(x2, tw2);
        Z[zmap2(q+768)] = cmul(x3, tw3);
    }
}
__device__ __forceinline__ void fft_stepB_wave(float2* Z, int lane){
    int nA = lane & 15, jv = lane >> 4;
    float2 a[16];
    #pragma unroll
    for (int u = 0; u < 16; ++u) a[u] = Z[zmap2(nA + 16*u + 256*jv)];
    fft16(a);
    float s_, c_;
    __sincosf(-2.0f*PI_F*(float)(nA*jv)*(1.0f/1024.0f), &s_, &c_);
    float2 tw = make_float2(c_, s_);
    __sincosf(-2.0f*PI_F*(float)nA*(1.0f/256.0f), &s_, &c_);
    float2 st = make_float2(c_, s_);
    #pragma unroll
    for (int ju = 0; ju < 16; ++ju){
        Z[zmap2(nA + 16*ju + 256*jv)] = cmul(a[((ju&3)<<2)|(ju>>2)], tw);
        tw = cmul(tw, st);
    }
}
__device__ __forceinline__ void fft_stepC_wave(float2* Z, int lane){
    int ju = (lane & 63) >> 2, jv = lane & 3;
    float2 a[16];
    #pragma unroll
    for (int nA = 0; nA < 16; ++nA) a[nA] = Z[zmap2(nA + 16*ju + 256*jv)];
    fft16(a);
    #pragma unroll
    for (int kO = 0; kO < 16; ++kO)
        Z[zmap2(kO + 16*ju + 256*jv)] = a[((kO&3)<<2)|(kO>>2)];
}

// ---------------- weight prep ----------------
__global__ __launch_bounds__(256) void prep_w(const float* __restrict__ w1,
                                              const float* __restrict__ w2,
                                              u16* __restrict__ WSW){
    int gid = blockIdx.x * 256 + threadIdx.x;
    int qd = gid >> 12;
    int t  = qd & 1;
    int n  = (qd >> 1) & 7;
    int l  = qd >> 4;
    int rr = gid & 4095;
    int o  = rr >> 6;
    int k  = rr & 63;
    const float* w = l ? w2 : w1;
    WSW[gid] = f2bf(w[((size_t)(t*8 + n)*64 + k)*64 + o]);
}

// Spectrum layout: S[SIDX * KPAD + k], SIDX = (((b*8+c)*8+n)*2+pl)*64 + p_local

__device__ __forceinline__ u16 unpack_one(const float2* Zc, int k, int pl, float sf){
    float2 Zk = Zc[sig(k)], Zm = Zc[sig(1024 - k)];
    float sn_, cs_; __sincosf(PI_F*(float)k*(1.0f/1024.0f), &sn_, &cs_);
    float Er=0.5f*(Zk.x+Zm.x), Ei=0.5f*(Zk.y-Zm.y);
    float Dr=0.5f*(Zk.x-Zm.x), Di=0.5f*(Zk.y+Zm.y);
    float Xr = Er + cs_*Di - sn_*Dr;
    float Xi = Ei - sn_*Di - cs_*Dr;
    return f2bf((pl ? Xi : Xr) * sf);
}

// ---------------- forward rfft(2048) ----------------
__global__ __launch_bounds__(256) void fwd_fft(const float* __restrict__ X,
                                               u16* __restrict__ S){
    __shared__ float2 Zs[4*SEQ];
    int tid = threadIdx.x;
    int blk = blockIdx.x;
    int b = blk >> 10;
    int q = blk & 1023;
    int m8 = q & 7, tq = q >> 3;
    int Q = (tq >> 2)*8 + m8, s4 = tq & 3;
    int col0 = Q*16 + s4*4;
    int p  = col0 >> 3;
    int c0 = col0 & 7;
    int n  = p >> 6, pl_ = p & 63;
    int wave = tid >> 6, lane = tid & 63;

    // fused load + pack + step A (registers), write to LDS
    float2 zz[4][4];   // [v][seq]
    #pragma unroll
    for (int v = 0; v < 4; ++v){
        int pi = tid + 256*v;
        size_t base = ((size_t)(b*2048 + 2*pi)*512 + p)*8 + c0;
        f32x4 ve = *(const f32x4*)(X + base);
        f32x4 vo = *(const f32x4*)(X + base + 4096);
        #pragma unroll
        for (int s = 0; s < 4; ++s) zz[v][s] = make_float2(ve[s], vo[s]);
    }
    {
        int u = (tid >> 4) & 15;
        float s_, c_;
        __sincosf(-2.0f*PI_F*(float)u*(1.0f/64.0f), &s_, &c_);
        float2 tw1 = make_float2(c_, s_);
        float2 tw2 = cmul(tw1, tw1);
        float2 tw3 = cmul(tw2, tw1);
        #pragma unroll
        for (int s = 0; s < 4; ++s){
            float2 x0 = zz[0][s], x1 = zz[1][s], x2 = zz[2][s], x3 = zz[3][s];
            fft4v(x0, x1, x2, x3);
            float2* Z = Zs + s*SEQ;
            Z[zmap2(tid)]     = x0;
            Z[zmap2(tid+256)] = cmul(x1, tw1);
            Z[zmap2(tid+512)] = cmul(x2, tw2);
            Z[zmap2(tid+768)] = cmul(x3, tw3);
        }
    }
    __syncthreads();                 // only cross-wave handoff in this kernel
    float2* Z = Zs + wave*SEQ;       // wave w owns seq w from here on
    fft_stepB_wave(Z, lane);
    WAVE_FENCE();
    fft_stepC_wave(Z, lane);
    WAVE_FENCE();
    // unpack + coalesced store: wave w = channel c0+w, pl = lane>>5
    const float sf = 0.02209708691207961f;     // 1/sqrt(2048)
    int pl = lane >> 5, tr = lane & 31;
    u16* rp = S + (size_t)((((b*8 + (c0+wave))*8 + n)*2 + pl)*64 + pl_)*KPAD;
    for (int kk = tr*2; kk <= 1024; kk += 64){
        u16 w0 = unpack_one(Z, kk, pl, sf);
        if (kk < 1024){
            u16 w1 = unpack_one(Z, kk+1, pl, sf);
            *(u32*)(rp + kk) = (u32)w0 | ((u32)w1 << 16);
        } else {
            rp[kk] = w0;
        }
    }
}

// ---------------- MLP (round-2 proven structure) ----------------
__device__ __forceinline__ bf16x8 fetchB(const u16* mat, int o64, int k64, bool neg){
    const u32x2* pb = (const u32x2*)(mat + o64*68 + k64);
    u32x2 lo = pb[0], hi = pb[1];
    union { u32 u[4]; bf16x8 v; } bt;
    bt.u[0]=lo.x; bt.u[1]=lo.y; bt.u[2]=hi.x; bt.u[3]=hi.y;
    if (neg){ bt.u[0]^=0x80008000u; bt.u[1]^=0x80008000u; bt.u[2]^=0x80008000u; bt.u[3]^=0x80008000u; }
    return bt.v;
}
__device__ __forceinline__ bf16x8 loadU16x8(const u16* pp){
    union { u32 u[4]; bf16x8 v; } t;
    const u32* qq = (const u32*)pp;
    t.u[0]=qq[0]; t.u[1]=qq[1]; t.u[2]=qq[2]; t.u[3]=qq[3];
    return t.v;
}

__global__ __launch_bounds__(256) void mlp_kernel(const u16* __restrict__ WSW,
                                                  const float* __restrict__ b1,
                                                  const float* __restrict__ b2,
                                                  u16* __restrict__ S){
    __shared__ __align__(16) u16 AT[4][64*68];
    __shared__ __align__(16) u16 AS[8448];
    int tid = threadIdx.x;
    int blk = blockIdx.x;
    int n = blk & 7;
    int rest = blk >> 3;               // [0,544) = 32 bc x 17 tiles
    int t17 = rest % 17;
    int bc  = rest / 17;
    int b = bc >> 3, c = bc & 7;
    int k0 = t17 << 6;
    int lane = tid & 63, wv = tid >> 6;
    int lane15 = lane & 15, quad = lane >> 4;

    for (int mi = 0; mi < 4; ++mi){
        const u32* src = (const u32*)(WSW + (size_t)(((mi>>1)*8 + n)*2 + (mi&1))*4096);
        u32* dstm = (u32*)AT[mi];
        for (int d = tid; d < 2048; d += 256){
            int o = d >> 5, kk2 = d & 31;
            dstm[o*34 + kk2] = src[d];
        }
    }
    float bb1[8], bb2v[8];
    #pragma unroll
    for (int nb = 0; nb < 8; ++nb){
        int col = nb*16 + lane15;
        int tt = col >> 6, cc = col & 63;
        bb1[nb]  = b1[tt*512 + n*64 + cc];
        bb2v[nb] = b2[tt*512 + n*64 + cc];
    }
    size_t SB = (size_t)(((b*8 + c)*8 + n)*2)*64;
    {
        int rsub = tid & 31;
        for (int rr = tid >> 5; rr < 128; rr += 8){
            const u16* rp = S + (SB + rr)*KPAD + k0;
            u32 w = *(const u32*)(rp + 2*rsub);
            AS[(2*rsub)*132 + rr]   = (u16)(w & 0xFFFFu);
            AS[(2*rsub+1)*132 + rr] = (u16)(w >> 16);
        }
    }
    __syncthreads();
    // ---- layer 1 ----
    const u16* arow = AS + (wv*16 + lane15)*132;
    bf16x8 afr[4];
    #pragma unroll
    for (int kb = 0; kb < 4; ++kb)
        afr[kb] = loadU16x8(arow + kb*32 + quad*8);
    f32x4 acc[8];
    #pragma unroll
    for (int nb = 0; nb < 8; ++nb){ acc[nb][0]=bb1[nb]; acc[nb][1]=bb1[nb]; acc[nb][2]=bb1[nb]; acc[nb][3]=bb1[nb]; }
    #pragma unroll
    for (int nb = 0; nb < 8; ++nb){
        int o64 = (nb&3)*16 + lane15;
        #pragma unroll
        for (int kb = 0; kb < 4; ++kb){
            int k64 = (kb&1)*32 + quad*8;
            const u16* mat; bool neg = false;
            if (kb < 2) mat = (nb<4) ? AT[0] : AT[1];
            else { if (nb<4){ mat = AT[1]; neg = true; } else mat = AT[0]; }
            acc[nb] = __builtin_amdgcn_mfma_f32_16x16x32_bf16(afr[kb], fetchB(mat,o64,k64,neg), acc[nb], 0,0,0);
        }
    }
    #pragma unroll
    for (int nb = 0; nb < 8; ++nb){
        #pragma unroll
        for (int r4 = 0; r4 < 4; ++r4){
            float xv = acc[nb][r4];
            float u_ = xv * 0.70710678118f;
            float u2 = u_*u_;
            float pg = 1.0f + u2*(-0.333333333f + u2*(0.1f + u2*(-0.0238095238f)));
            float h  = 0.5f * xv * (1.0f + 1.12837916709551f * u_ * pg);
            AS[(wv*16 + quad*4 + r4)*132 + nb*16 + lane15] = f2bf(h);
        }
    }
    // ---- layer 2 ----
    bf16x8 a2[4];
    #pragma unroll
    for (int kb = 0; kb < 4; ++kb)
        a2[kb] = loadU16x8(arow + kb*32 + quad*8);
    f32x4 acc2[8];
    #pragma unroll
    for (int nb = 0; nb < 8; ++nb){ acc2[nb][0]=bb2v[nb]; acc2[nb][1]=bb2v[nb]; acc2[nb][2]=bb2v[nb]; acc2[nb][3]=bb2v[nb]; }
    #pragma unroll
    for (int nb = 0; nb < 8; ++nb){
        int o64 = (nb&3)*16 + lane15;
        #pragma unroll
        for (int kb = 0; kb < 4; ++kb){
            int k64 = (kb&1)*32 + quad*8;
            const u16* mat; bool neg = false;
            if (kb < 2) mat = (nb<4) ? AT[2] : AT[3];
            else { if (nb<4){ mat = AT[3]; neg = true; } else mat = AT[2]; }
            acc2[nb] = __builtin_amdgcn_mfma_f32_16x16x32_bf16(a2[kb], fetchB(mat,o64,k64,neg), acc2[nb], 0,0,0);
        }
    }
    __syncthreads();
    #pragma unroll
    for (int nb = 0; nb < 8; ++nb){
        #pragma unroll
        for (int r4 = 0; r4 < 4; ++r4)
            AS[(nb*16 + lane15)*66 + (wv*16 + quad*4 + r4)] = f2bf(acc2[nb][r4]);
    }
    __syncthreads();
    {
        int rsub = tid & 31;
        int k = k0 + 2*rsub;
        for (int rr = tid >> 5; rr < 128; rr += 8){
            u32 val = *(const u32*)(AS + rr*66 + 2*rsub);
            u16* rp = S + (SB + rr)*KPAD + k0;
            if (k + 1 <= 1024)  *(u32*)(rp + 2*rsub) = val;
            else if (k == 1024) rp[2*rsub] = (u16)(val & 0xFFFFu);
        }
    }
}

// ---------------- inverse irfft(2048) + residual ----------------
__global__ __launch_bounds__(256) void inv_fft(const u16* __restrict__ S,
                                               const float* __restrict__ X,
                                               float* __restrict__ OUT){
    __shared__ float2 Zs[4*SEQ];
    __shared__ float2 ysp[4];
    int tid = threadIdx.x;
    int blk = blockIdx.x;
    int b = blk >> 10;
    int q = blk & 1023;
    int m8 = q & 7, tq = q >> 3;
    int Q = (tq >> 2)*8 + m8, s4 = tq & 3;
    int col0 = Q*16 + s4*4;
    int p  = col0 >> 3;
    int c0 = col0 & 7;
    int n  = p >> 6, pl_ = p & 63;
    int wave = tid >> 6, lane = tid & 63;

    // prefetch residual X into registers (overlaps the whole FFT)
    f32x4 xe[4], xo[4];
    #pragma unroll
    for (int i = 0; i < 4; ++i){
        int pi = tid + 256*i;
        size_t base = ((size_t)(b*2048 + 2*pi)*512 + p)*8 + c0;
        xe[i] = *(const f32x4*)(X + base);
        xo[i] = *(const f32x4*)(X + base + 4096);
    }

    // wave-local spectrum load: wave g = channel c0+g
    float2* Z = Zs + wave*SEQ;
    {
        const u16* rpR = S + (size_t)((((b*8 + (c0+wave))*8 + n)*2 + 0)*64 + pl_)*KPAD;
        const u16* rpI = rpR + (size_t)64*KPAD;
        for (int kk = 2*lane; kk <= 1024; kk += 128){
            u32 wr = *(const u32*)(rpR + kk);
            u32 wi = *(const u32*)(rpI + kk);
            float yr0 = bf2f((u16)(wr & 0xFFFFu));
            float yi0 = bf2f((u16)(wi & 0xFFFFu));
            if (kk == 0)         Z[zmap2(0)] = make_float2(yr0, 0.0f);
            else if (kk == 1024) ysp[wave] = make_float2(yr0, 0.0f);
            else                 Z[zmap2(kk)] = make_float2(yr0, yi0);
            if (kk < 1024){
                float yr1 = bf2f((u16)(wr >> 16));
                float yi1 = bf2f((u16)(wi >> 16));
                Z[zmap2(kk+1)] = make_float2(yr1, yi1);
            }
        }
    }
    WAVE_FENCE();
    // wave-local hermitian pre-process: Z[k] = E + i*(e^{+i pi k/1024} * D)
    for (int i = 0; i < 9; ++i){
        int k = lane + 64*i;
        if (k <= 512){
            float s2_, c2_; __sincosf(PI_F*(float)k*(1.0f/1024.0f), &s2_, &c2_);
            float2 Yk = Z[zmap2(k)];
            float2 Ym = (k == 0) ? ysp[wave] : Z[zmap2(1024 - k)];
            float Ex = 0.5f*(Yk.x + Ym.x);
            float Ey = 0.5f*(Yk.y - Ym.y);
            float Dx = 0.5f*(Yk.x - Ym.x);
            float Dy = 0.5f*(Yk.y + Ym.y);
            float Ox = c2_*Dx - s2_*Dy;
            float Oy = c2_*Dy + s2_*Dx;
            Z[zmap2(k)] = make_float2(Ex - Oy, Ey + Ox);
            if (k > 0 && k < 512)
                Z[zmap2(1024 - k)] = make_float2(Ex + Oy, Ox - Ey);
        }
    }
    WAVE_FENCE();
    fft_stepA_wave(Z, lane);
    WAVE_FENCE();
    fft_stepB_wave(Z, lane);
    WAVE_FENCE();
    fft_stepC_wave(Z, lane);
    __syncthreads();                 // only cross-wave handoff: final gather reads all 4 seqs
    // unpack (index reversal) + residual + float4 store
    const float sc = 0.04419417382415922f;   // sqrt(2048)/1024
    #pragma unroll
    for (int i = 0; i < 4; ++i){
        int pi = tid + 256*i;
        int zb = sig(1024 - pi);
        size_t base = ((size_t)(b*2048 + 2*pi)*512 + p)*8 + c0;
        f32x4 oe, oo;
        #pragma unroll
        for (int s = 0; s < 4; ++s){
            float2 r = Zs[s*SEQ + zb];
            oe[s] = r.x*sc + xe[i][s];
            oo[s] = r.y*sc + xo[i][s];
        }
        *(f32x4*)(OUT + base)        = oe;
        *(f32x4*)(OUT + base + 4096) = oo;
    }
}

extern "C" void kernel_launch(void* const* d_in, const int* in_sizes, int n_in,
                              void* d_out, int out_size, void* d_ws, size_t ws_size,
                              hipStream_t stream){
    (void)in_sizes; (void)n_in; (void)out_size; (void)ws_size;
    const float* x  = (const float*)d_in[0];
    const float* w1 = (const float*)d_in[1];
    const float* b1 = (const float*)d_in[2];
    const float* w2 = (const float*)d_in[3];
    const float* b2 = (const float*)d_in[4];
    float* out = (float*)d_out;
    u16* WSW = (u16*)d_ws;
    u16* S1  = (u16*)((char*)d_ws + (1 << 20));

    prep_w<<<dim3(512),  dim3(256), 0, stream>>>(w1, w2, WSW);
    fwd_fft<<<dim3(4096), dim3(256), 0, stream>>>(x, S1);
    mlp_kernel<<<dim3(4352), dim3(256), 0, stream>>>(WSW, b1, b2, S1);
    inv_fft<<<dim3(4096), dim3(256), 0, stream>>>(S1, x, out);
}